// Round 10
// baseline (24546.799 us; speedup 1.0000x reference)
//
#include <hip/hip_runtime.h>

#define DIM 64
#define NN 20000
#define NE 50000
#define NG 256
#define CONV_STEPS 12
#define S2S 3

typedef float floatx4 __attribute__((ext_vector_type(4)));
typedef short short8 __attribute__((ext_vector_type(8)));

__device__ __forceinline__ unsigned short f2bf(float f) {
    unsigned u = __float_as_uint(f);
    unsigned r = (u + 0x7fffu + ((u >> 16) & 1u)) >> 16;
    return (unsigned short)r;
}
__device__ __forceinline__ float bf2f(unsigned short h) {
    return __uint_as_float((unsigned)h << 16);
}
__device__ __forceinline__ float sigmoidf(float x) { return 1.f / (1.f + __expf(-x)); }
__device__ __forceinline__ float tanh_fast(float x) {
    float ax = fabsf(x);
    float t = __expf(-2.f * ax);
    float r = (1.f - t) / (1.f + t);
    return copysignf(r, x);
}
__device__ __forceinline__ float leaky(float v) { return v > 0.f ? v : 0.01f * v; }

// ---- prep: W2 -> bf16 fragment order; GRU/root weights -> bf16 hi/lo ----
// W2 fragment order: o-tile jt=j>>4, k-chunk kc=k>>5, lane l=kq*16+row holds
// W2[jt*16+row, kc*32+kq*8..+8]; flat dst ((jt*4+kc)*64+l)*8+kb.
__global__ __launch_bounds__(256) void prep_kernel(const float* __restrict__ w2,
        const float* __restrict__ wih, const float* __restrict__ whh,
        const float* __restrict__ rootw,
        unsigned short* __restrict__ w2f,
        unsigned short* __restrict__ wih_hi, unsigned short* __restrict__ wih_lo,
        unsigned short* __restrict__ whh_hi, unsigned short* __restrict__ whh_lo,
        unsigned short* __restrict__ rt_hi, unsigned short* __restrict__ rt_lo) {
    int idx = blockIdx.x * 256 + threadIdx.x;
    const int W2N = 4096 * 128, GT = 192 * 64;
    if (idx < W2N) {
        int j = idx >> 7, k = idx & 127;
        int jt = j >> 4, rw = j & 15;
        int kc = k >> 5, kq = (k >> 3) & 3, kb = k & 7;
        int dst = (((jt * 4 + kc) * 64) + kq * 16 + rw) * 8 + kb;
        w2f[dst] = f2bf(w2[idx]);
    } else if (idx < W2N + GT) {
        int t = idx - W2N;
        float v = wih[t];
        unsigned short h = f2bf(v);
        wih_hi[t] = h; wih_lo[t] = f2bf(v - bf2f(h));
    } else if (idx < W2N + 2 * GT) {
        int t = idx - W2N - GT;
        float v = whh[t];
        unsigned short h = f2bf(v);
        whh_hi[t] = h; whh_lo[t] = f2bf(v - bf2f(h));
    } else if (idx < W2N + 2 * GT + 4096) {
        int t = idx - W2N - 2 * GT;
        int o = t >> 6, k = t & 63;
        float v = rootw[k * 64 + o];          // rootT[o][k] = root_w[k][o]
        unsigned short h = f2bf(v);
        rt_hi[t] = h; rt_lo[t] = f2bf(v - bf2f(h));
    }
}

// ---- h1 = leaky(edge_attr @ net_w1.T + b1), bf16 [NE,128] ----
__global__ __launch_bounds__(256) void h1_kernel(const float* __restrict__ ea,
        const float* __restrict__ w1, const float* __restrict__ b1, unsigned short* __restrict__ h1) {
    int idx = blockIdx.x * 256 + threadIdx.x;
    if (idx >= NE * 128) return;
    int e = idx >> 7, k = idx & 127;
    const float* a = ea + (size_t)e * 4;
    const float* w = w1 + (size_t)k * 4;
    float acc = b1[k] + a[0] * w[0] + a[1] * w[1] + a[2] * w[2] + a[3] * w[3];
    h1[idx] = f2bf(leaky(acc));
}

// ---- lin0: X = leaky(x @ lin0_w.T + b), f32 [NN,64]; wave per node ----
__global__ __launch_bounds__(256) void lin0_kernel(const float* __restrict__ x,
        const float* __restrict__ w, const float* __restrict__ b, float* __restrict__ X) {
    int gid = blockIdx.x * 256 + threadIdx.x;
    int n = gid >> 6, o = gid & 63;
    if (n >= NN) return;
    float acc = b[o];
    const float* xr = x + (size_t)n * 72;
    const float* wr = w + (size_t)o * 72;
    #pragma unroll 8
    for (int i = 0; i < 72; ++i) acc += xr[i] * wr[i];
    X[(size_t)n * 64 + o] = leaky(acc);
}

// ---- XB2[n,o] = sum_i X[n,i] * b2[i*64+o] ----
__global__ __launch_bounds__(256) void xb2_kernel(const float* __restrict__ X,
        const float* __restrict__ b2, float* __restrict__ XB2) {
    int gid = blockIdx.x * 256 + threadIdx.x;
    int n = gid >> 6, lane = gid & 63;
    if (n >= NN) return;
    float xv = X[(size_t)n * 64 + lane];
    float acc = 0.f;
    #pragma unroll 8
    for (int i = 0; i < 64; ++i) acc += __shfl(xv, i) * b2[i * 64 + lane];
    XB2[(size_t)n * 64 + lane] = acc;
}

// ---- degree of dst nodes ----
__global__ __launch_bounds__(256) void deg_kernel(const int* __restrict__ ei, float* __restrict__ deg) {
    int e = blockIdx.x * 256 + threadIdx.x;
    if (e < NE) atomicAdd(&deg[ei[NE + e]], 1.f);
}

// ---- per-graph node range starts (batch is sorted) ----
__global__ void gstart_kernel(const int* __restrict__ batch, int* __restrict__ gstart) {
    int g = blockIdx.x * blockDim.x + threadIdx.x;
    if (g > NG) return;
    int lo = 0, hi = NN;
    while (lo < hi) { int mid = (lo + hi) >> 1; if (batch[mid] < g) lo = mid + 1; else hi = mid; }
    gstart[g] = lo;
}

// ---- fused edge messages v5: barrier-free K-loop; coalesced fragment-order
//      B-loads with explicit 1-il register prefetch (latency cover).
__global__ __launch_bounds__(256, 3) void edge_msg_fused(
        const unsigned short* __restrict__ h1,   // [NE,128] bf16
        const unsigned short* __restrict__ w2f,  // fragment order
        const float* __restrict__ XB2,           // [NN,64] f32 bias term
        const float* __restrict__ X,             // [NN,64] f32
        const int* __restrict__ ei, float* __restrict__ agg) {
    __shared__ float xs_t[32][64];               // [ib_local][edge_local] 8 KB
    int tid = threadIdx.x;
    int e0b = blockIdx.x * 64;
    int ibBase = blockIdx.y * 32;
    bool useBias = (blockIdx.y == 0);

    {   // stage X transposed
        int e_l = tid & 63, q = tid >> 6;
        int e = e0b + e_l; if (e >= NE) e = NE - 1;
        int src = ei[e];
        const float4* xr = (const float4*)(X + (size_t)src * 64 + ibBase + q * 8);
        float4 v0 = xr[0], v1 = xr[1];
        int f0 = q * 8;
        xs_t[f0 + 0][e_l] = v0.x; xs_t[f0 + 1][e_l] = v0.y;
        xs_t[f0 + 2][e_l] = v0.z; xs_t[f0 + 3][e_l] = v0.w;
        xs_t[f0 + 4][e_l] = v1.x; xs_t[f0 + 5][e_l] = v1.y;
        xs_t[f0 + 6][e_l] = v1.z; xs_t[f0 + 7][e_l] = v1.w;
    }

    int wv = tid >> 6, lane = tid & 63;
    int oh = wv;
    int row = lane & 15, kq = lane >> 4;

    // A-frags hoisted
    short8 afr[4][4];
    #pragma unroll
    for (int mt = 0; mt < 4; ++mt) {
        int e = e0b + mt * 16 + row; if (e >= NE) e = NE - 1;
        const short8* ap = (const short8*)(h1 + (size_t)e * 128 + kq * 8);
        #pragma unroll
        for (int kc = 0; kc < 4; ++kc) afr[mt][kc] = ap[kc * 4];
    }

    floatx4 msg[4];
    #pragma unroll
    for (int mt = 0; mt < 4; ++mt) {
        #pragma unroll
        for (int r = 0; r < 4; ++r) {
            int e = e0b + mt * 16 + kq * 4 + r; if (e >= NE) e = NE - 1;
            msg[mt][r] = useBias ? XB2[(size_t)ei[e] * 64 + oh * 16 + row] : 0.f;
        }
    }

    __syncthreads();   // xs_t ready (only barrier)

    const short8* bp = (const short8*)w2f + ((size_t)(ibBase * 4 + oh)) * 256 + lane;
    short8 c0 = bp[0], c1b = bp[64], c2b = bp[128], c3b = bp[192];
    for (int il = 0; il < 32; ++il) {
        short8 p0, p1, p2, p3;
        if (il < 31) {                  // prefetch next il's B-frags (tile + 4)
            const short8* np = bp + 1024;
            p0 = np[0]; p1 = np[64]; p2 = np[128]; p3 = np[192];
            bp = np;
        }
        float4 xv[4];
        #pragma unroll
        for (int mt = 0; mt < 4; ++mt)
            xv[mt] = *(const float4*)&xs_t[il][mt * 16 + kq * 4];
        #pragma unroll
        for (int mt = 0; mt < 4; ++mt) {
            floatx4 acc = {0.f, 0.f, 0.f, 0.f};
            acc = __builtin_amdgcn_mfma_f32_16x16x32_bf16(afr[mt][0], c0, acc, 0, 0, 0);
            acc = __builtin_amdgcn_mfma_f32_16x16x32_bf16(afr[mt][1], c1b, acc, 0, 0, 0);
            acc = __builtin_amdgcn_mfma_f32_16x16x32_bf16(afr[mt][2], c2b, acc, 0, 0, 0);
            acc = __builtin_amdgcn_mfma_f32_16x16x32_bf16(afr[mt][3], c3b, acc, 0, 0, 0);
            msg[mt][0] += xv[mt].x * acc[0];
            msg[mt][1] += xv[mt].y * acc[1];
            msg[mt][2] += xv[mt].z * acc[2];
            msg[mt][3] += xv[mt].w * acc[3];
        }
        if (il < 31) { c0 = p0; c1b = p1; c2b = p2; c3b = p3; }
    }

    #pragma unroll
    for (int mt = 0; mt < 4; ++mt) {
        #pragma unroll
        for (int r = 0; r < 4; ++r) {
            int e = e0b + mt * 16 + kq * 4 + r;
            if (e < NE) {
                int dst = ei[NE + e];
                atomicAdd(&agg[(size_t)dst * 64 + oh * 16 + row], msg[mt][r]);
            }
        }
    }
}

// ---- node update v2: MFMA (bf16 hi/lo 3-product ~ f32 exact) ----
// block = 256 thr (4 waves), 64 nodes. wave wv owns feature-slice wv*16..+15.
// GEMM1: C1 = X @ rootT^T(o,k);  m = leaky(agg/deg + C1 + conv_b)
// GEMM2: 6 gate tiles (ir,iz,in from m@Wih; hr,hz,hn from X@Whh), GRU elementwise.
__global__ __launch_bounds__(256) void node_update(float* __restrict__ X, float* __restrict__ agg,
        const float* __restrict__ deg,
        const unsigned short* __restrict__ rt_hi, const unsigned short* __restrict__ rt_lo,
        const unsigned short* __restrict__ wih_hi, const unsigned short* __restrict__ wih_lo,
        const unsigned short* __restrict__ whh_hi, const unsigned short* __restrict__ whh_lo,
        const float* __restrict__ conv_b,
        const float* __restrict__ bih, const float* __restrict__ bhh) {
    __shared__ unsigned short Xhi[64 * 72], Xlo[64 * 72];   // padded stride 72
    __shared__ unsigned short Mhi[64 * 72], Mlo[64 * 72];
    __shared__ float Xf[64 * 68];                            // padded stride 68
    int tid = threadIdx.x;
    int n0 = blockIdx.x * 64;

    // stage X (f32 + bf16 hi/lo)
    for (int t = tid; t < 1024; t += 256) {
        int node = t >> 4, c = (t & 15) * 4;
        int n = n0 + node; if (n >= NN) n = NN - 1;
        float4 v = *(const float4*)(X + (size_t)n * 64 + c);
        float vv[4] = {v.x, v.y, v.z, v.w};
        #pragma unroll
        for (int j = 0; j < 4; ++j) {
            float xv = vv[j];
            unsigned short h = f2bf(xv);
            Xhi[node * 72 + c + j] = h;
            Xlo[node * 72 + c + j] = f2bf(xv - bf2f(h));
            Xf[node * 68 + c + j] = xv;
        }
    }
    __syncthreads();

    int wv = tid >> 6, lane = tid & 63;
    int row = lane & 15, kq = lane >> 4;
    int ocol = wv * 16 + row;

    // GEMM1: X @ rootT
    floatx4 c1[4];
    #pragma unroll
    for (int mt = 0; mt < 4; ++mt) c1[mt] = (floatx4){0.f, 0.f, 0.f, 0.f};
    #pragma unroll
    for (int kc = 0; kc < 2; ++kc) {
        short8 bh = *(const short8*)(rt_hi + ocol * 64 + kc * 32 + kq * 8);
        short8 bl = *(const short8*)(rt_lo + ocol * 64 + kc * 32 + kq * 8);
        #pragma unroll
        for (int mt = 0; mt < 4; ++mt) {
            short8 ah = *(const short8*)&Xhi[(mt * 16 + row) * 72 + kc * 32 + kq * 8];
            short8 al = *(const short8*)&Xlo[(mt * 16 + row) * 72 + kc * 32 + kq * 8];
            c1[mt] = __builtin_amdgcn_mfma_f32_16x16x32_bf16(ah, bh, c1[mt], 0, 0, 0);
            c1[mt] = __builtin_amdgcn_mfma_f32_16x16x32_bf16(al, bh, c1[mt], 0, 0, 0);
            c1[mt] = __builtin_amdgcn_mfma_f32_16x16x32_bf16(ah, bl, c1[mt], 0, 0, 0);
        }
    }

    // m = leaky(agg/deg + C1 + cb); stage m hi/lo to LDS
    float cb = conv_b[ocol];
    #pragma unroll
    for (int mt = 0; mt < 4; ++mt) {
        #pragma unroll
        for (int r = 0; r < 4; ++r) {
            int node = mt * 16 + kq * 4 + r;
            int gn = n0 + node;
            float aggv = 0.f, dv = 1.f;
            if (gn < NN) {
                size_t id = (size_t)gn * 64 + ocol;
                aggv = agg[id]; agg[id] = 0.f;      // re-zero for next step
                dv = fmaxf(deg[gn], 1.f);
            }
            float m = leaky(aggv / dv + c1[mt][r] + cb);
            unsigned short h = f2bf(m);
            Mhi[node * 72 + ocol] = h;
            Mlo[node * 72 + ocol] = f2bf(m - bf2f(h));
        }
    }
    __syncthreads();

    // GEMM2: 6 gate tiles
    floatx4 gir[4], giz[4], gin[4], ghr[4], ghz[4], ghn[4];
    #pragma unroll
    for (int mt = 0; mt < 4; ++mt) {
        gir[mt] = (floatx4){0.f,0.f,0.f,0.f}; giz[mt] = gir[mt]; gin[mt] = gir[mt];
        ghr[mt] = gir[mt]; ghz[mt] = gir[mt]; ghn[mt] = gir[mt];
    }
    #define GATE_GEMM(ACC, WHI, WLO, AHI, ALO, ROFF)                                   \
    {                                                                                  \
        _Pragma("unroll")                                                              \
        for (int kc = 0; kc < 2; ++kc) {                                               \
            short8 bh = *(const short8*)((WHI) + ((ROFF) + ocol) * 64 + kc * 32 + kq * 8); \
            short8 bl = *(const short8*)((WLO) + ((ROFF) + ocol) * 64 + kc * 32 + kq * 8); \
            _Pragma("unroll")                                                          \
            for (int mt = 0; mt < 4; ++mt) {                                           \
                short8 ah = *(const short8*)&(AHI)[(mt * 16 + row) * 72 + kc * 32 + kq * 8]; \
                short8 al = *(const short8*)&(ALO)[(mt * 16 + row) * 72 + kc * 32 + kq * 8]; \
                ACC[mt] = __builtin_amdgcn_mfma_f32_16x16x32_bf16(ah, bh, ACC[mt], 0, 0, 0); \
                ACC[mt] = __builtin_amdgcn_mfma_f32_16x16x32_bf16(al, bh, ACC[mt], 0, 0, 0); \
                ACC[mt] = __builtin_amdgcn_mfma_f32_16x16x32_bf16(ah, bl, ACC[mt], 0, 0, 0); \
            }                                                                          \
        }                                                                              \
    }
    GATE_GEMM(gir, wih_hi, wih_lo, Mhi, Mlo, 0)
    GATE_GEMM(giz, wih_hi, wih_lo, Mhi, Mlo, 64)
    GATE_GEMM(gin, wih_hi, wih_lo, Mhi, Mlo, 128)
    GATE_GEMM(ghr, whh_hi, whh_lo, Xhi, Xlo, 0)
    GATE_GEMM(ghz, whh_hi, whh_lo, Xhi, Xlo, 64)
    GATE_GEMM(ghn, whh_hi, whh_lo, Xhi, Xlo, 128)
    #undef GATE_GEMM

    // GRU elementwise (lane-local: node = mt*16+kq*4+r, feat = ocol)
    float bi0 = bih[ocol], bi1 = bih[64 + ocol], bi2 = bih[128 + ocol];
    float bh0 = bhh[ocol], bh1 = bhh[64 + ocol], bh2 = bhh[128 + ocol];
    #pragma unroll
    for (int mt = 0; mt < 4; ++mt) {
        #pragma unroll
        for (int r = 0; r < 4; ++r) {
            int node = mt * 16 + kq * 4 + r;
            int gn = n0 + node;
            float rr = sigmoidf(gir[mt][r] + bi0 + ghr[mt][r] + bh0);
            float zz = sigmoidf(giz[mt][r] + bi1 + ghz[mt][r] + bh1);
            float nn = tanh_fast(gin[mt][r] + bi2 + rr * (ghn[mt][r] + bh2));
            float xs = Xf[node * 68 + ocol];
            if (gn < NN) X[(size_t)gn * 64 + ocol] = (1.f - zz) * nn + zz * xs;
        }
    }
}

// ---- set2set LSTM step; block per graph ----
__global__ __launch_bounds__(256) void lstm_kernel(const float* __restrict__ qstar,
        float* __restrict__ hl, float* __restrict__ cl,
        const float* __restrict__ wih, const float* __restrict__ whh,
        const float* __restrict__ bih, const float* __restrict__ bhh) {
    int g = blockIdx.x, tid = threadIdx.x;
    __shared__ float qs[128], hs[64], gates[256];
    if (tid < 128) qs[tid] = qstar[(size_t)g * 128 + tid];
    else if (tid < 192) hs[tid - 128] = hl[(size_t)g * 64 + tid - 128];
    __syncthreads();
    float acc = bih[tid] + bhh[tid];
    const float* wr = wih + (size_t)tid * 128;
    #pragma unroll 8
    for (int k = 0; k < 128; ++k) acc += qs[k] * wr[k];
    const float* wr2 = whh + (size_t)tid * 64;
    #pragma unroll 8
    for (int k = 0; k < 64; ++k) acc += hs[k] * wr2[k];
    gates[tid] = acc;
    __syncthreads();
    if (tid < 64) {
        float gi = gates[tid], gf = gates[64 + tid], gg = gates[128 + tid], go = gates[192 + tid];
        float c = sigmoidf(gf) * cl[(size_t)g * 64 + tid] + sigmoidf(gi) * tanh_fast(gg);
        float h = sigmoidf(go) * tanh_fast(c);
        cl[(size_t)g * 64 + tid] = c;
        hl[(size_t)g * 64 + tid] = h;
    }
}

// ---- e[n] = dot(X[n], hl[batch[n]]); wave per node ----
__global__ __launch_bounds__(256) void e_kernel(const float* __restrict__ X, const float* __restrict__ hl,
        const int* __restrict__ batch, float* __restrict__ ev) {
    int gid = blockIdx.x * 256 + threadIdx.x;
    int n = gid >> 6, lane = gid & 63;
    if (n >= NN) return;
    int g = batch[n];
    float v = X[(size_t)n * 64 + lane] * hl[(size_t)g * 64 + lane];
    #pragma unroll
    for (int m = 32; m >= 1; m >>= 1) v += __shfl_xor(v, m);
    if (lane == 0) ev[n] = v;
}

// ---- per-graph softmax-attention readout ----
__global__ __launch_bounds__(256) void pool_kernel(const float* __restrict__ X, const float* __restrict__ ev,
        const float* __restrict__ hl, const int* __restrict__ gstart, float* __restrict__ qstar) {
    int g = blockIdx.x, tid = threadIdx.x;
    int s0 = gstart[g], s1 = gstart[g + 1];
    __shared__ float red[256];
    __shared__ float sh_max, sh_sum;
    float lm = -3.0e38f;
    for (int n = s0 + tid; n < s1; n += 256) lm = fmaxf(lm, ev[n]);
    red[tid] = lm; __syncthreads();
    for (int s = 128; s > 0; s >>= 1) { if (tid < s) red[tid] = fmaxf(red[tid], red[tid + s]); __syncthreads(); }
    if (tid == 0) sh_max = red[0];
    __syncthreads();
    float mx = sh_max;
    float ls = 0.f;
    for (int n = s0 + tid; n < s1; n += 256) ls += __expf(ev[n] - mx);
    __syncthreads();
    red[tid] = ls; __syncthreads();
    for (int s = 128; s > 0; s >>= 1) { if (tid < s) red[tid] += red[tid + s]; __syncthreads(); }
    if (tid == 0) sh_sum = red[0];
    __syncthreads();
    float inv = 1.f / (sh_sum + 1e-16f);
    int wv = tid >> 6, lane = tid & 63;
    float fa = 0.f;
    for (int n = s0 + wv; n < s1; n += 4) fa += __expf(ev[n] - mx) * inv * X[(size_t)n * 64 + lane];
    __syncthreads();
    red[tid] = fa; __syncthreads();
    if (tid < 64) {
        float r = red[tid] + red[64 + tid] + red[128 + tid] + red[192 + tid];
        qstar[(size_t)g * 128 + 64 + tid] = r;
        qstar[(size_t)g * 128 + tid] = hl[(size_t)g * 64 + tid];
    }
}

// ---- final: out[g] = q_star[g] . lin3_w + b ----
__global__ __launch_bounds__(256) void final_kernel(const float* __restrict__ qstar,
        const float* __restrict__ w3, const float* __restrict__ b3, float* __restrict__ out) {
    int gid = blockIdx.x * 256 + threadIdx.x;
    int g = gid >> 6, lane = gid & 63;
    if (g >= NG) return;
    float v = qstar[(size_t)g * 128 + lane] * w3[lane] + qstar[(size_t)g * 128 + 64 + lane] * w3[64 + lane];
    #pragma unroll
    for (int m = 32; m >= 1; m >>= 1) v += __shfl_xor(v, m);
    if (lane == 0) out[g] = v + b3[0];
}

extern "C" void kernel_launch(void* const* d_in, const int* in_sizes, int n_in,
                              void* d_out, int out_size, void* d_ws, size_t ws_size,
                              hipStream_t stream) {
    const float* x        = (const float*)d_in[0];
    const float* ea       = (const float*)d_in[1];
    const int*   ei       = (const int*)d_in[2];
    const int*   batch    = (const int*)d_in[3];
    const float* lin0_w   = (const float*)d_in[4];
    const float* lin0_b   = (const float*)d_in[5];
    const float* net_w1   = (const float*)d_in[6];
    const float* net_b1   = (const float*)d_in[7];
    const float* net_w2   = (const float*)d_in[8];
    const float* net_b2   = (const float*)d_in[9];
    const float* root_w   = (const float*)d_in[10];
    const float* conv_b   = (const float*)d_in[11];
    const float* gru_w_ih = (const float*)d_in[12];
    const float* gru_w_hh = (const float*)d_in[13];
    const float* gru_b_ih = (const float*)d_in[14];
    const float* gru_b_hh = (const float*)d_in[15];
    const float* lstm_w_ih= (const float*)d_in[16];
    const float* lstm_w_hh= (const float*)d_in[17];
    const float* lstm_b_ih= (const float*)d_in[18];
    const float* lstm_b_hh= (const float*)d_in[19];
    const float* lin3_w   = (const float*)d_in[20];
    const float* lin3_b   = (const float*)d_in[21];
    float* out = (float*)d_out;

    char* base = (char*)d_ws;
    size_t off = 0;
    auto alloc = [&](size_t b) { size_t o = off; off += (b + 255) & ~(size_t)255; return o; };
    size_t o_h1    = alloc((size_t)NE * 128 * 2);
    size_t o_X     = alloc((size_t)NN * 64 * 4);
    size_t o_agg   = alloc((size_t)NN * 64 * 4);
    size_t o_xb2   = alloc((size_t)NN * 64 * 4);
    size_t o_deg   = alloc((size_t)NN * 4);
    size_t o_ev    = alloc((size_t)NN * 4);
    size_t o_s2s   = alloc((size_t)(NG * 128 + NG * 64 + NG * 64) * 4);
    size_t o_gst   = alloc((size_t)(NG + 1) * 4);
    size_t o_w2f   = alloc((size_t)4096 * 128 * 2);
    size_t o_wihh  = alloc((size_t)192 * 64 * 2);
    size_t o_wihl  = alloc((size_t)192 * 64 * 2);
    size_t o_whhh  = alloc((size_t)192 * 64 * 2);
    size_t o_whhl  = alloc((size_t)192 * 64 * 2);
    size_t o_rth   = alloc((size_t)64 * 64 * 2);
    size_t o_rtl   = alloc((size_t)64 * 64 * 2);
    if (ws_size < off) return;  // needs ~32 MB

    unsigned short* h1   = (unsigned short*)(base + o_h1);
    float* X    = (float*)(base + o_X);
    float* agg  = (float*)(base + o_agg);
    float* XB2  = (float*)(base + o_xb2);
    float* deg  = (float*)(base + o_deg);
    float* ev   = (float*)(base + o_ev);
    float* qstar= (float*)(base + o_s2s);
    float* hl   = qstar + NG * 128;
    float* cl   = hl + NG * 64;
    int*   gst  = (int*)(base + o_gst);
    unsigned short* w2f    = (unsigned short*)(base + o_w2f);
    unsigned short* wih_hi = (unsigned short*)(base + o_wihh);
    unsigned short* wih_lo = (unsigned short*)(base + o_wihl);
    unsigned short* whh_hi = (unsigned short*)(base + o_whhh);
    unsigned short* whh_lo = (unsigned short*)(base + o_whhl);
    unsigned short* rt_hi  = (unsigned short*)(base + o_rth);
    unsigned short* rt_lo  = (unsigned short*)(base + o_rtl);

    hipMemsetAsync(deg, 0, (size_t)NN * 4, stream);
    hipMemsetAsync(agg, 0, (size_t)NN * 64 * 4, stream);
    hipMemsetAsync(qstar, 0, (size_t)(NG * 128 + NG * 64 + NG * 64) * 4, stream);

    const int PREP_N = 4096 * 128 + 2 * 192 * 64 + 64 * 64;
    prep_kernel<<<(PREP_N + 255) / 256, 256, 0, stream>>>(
        net_w2, gru_w_ih, gru_w_hh, root_w, w2f,
        wih_hi, wih_lo, whh_hi, whh_lo, rt_hi, rt_lo);
    h1_kernel<<<(NE * 128 + 255) / 256, 256, 0, stream>>>(ea, net_w1, net_b1, h1);
    lin0_kernel<<<(NN * 64 + 255) / 256, 256, 0, stream>>>(x, lin0_w, lin0_b, X);
    deg_kernel<<<(NE + 255) / 256, 256, 0, stream>>>(ei, deg);
    gstart_kernel<<<2, 256, 0, stream>>>(batch, gst);

    const dim3 EGRID((NE + 63) / 64, 2);
    const int NBLK = (NN + 63) / 64;
    for (int s = 0; s < CONV_STEPS; ++s) {
        xb2_kernel<<<(NN * 64 + 255) / 256, 256, 0, stream>>>(X, net_b2, XB2);
        edge_msg_fused<<<EGRID, 256, 0, stream>>>(h1, w2f, XB2, X, ei, agg);
        node_update<<<NBLK, 256, 0, stream>>>(
            X, agg, deg, rt_hi, rt_lo, wih_hi, wih_lo, whh_hi, whh_lo,
            conv_b, gru_b_ih, gru_b_hh);
    }

    for (int s = 0; s < S2S; ++s) {
        lstm_kernel<<<NG, 256, 0, stream>>>(qstar, hl, cl, lstm_w_ih, lstm_w_hh, lstm_b_ih, lstm_b_hh);
        e_kernel<<<(NN * 64 + 255) / 256, 256, 0, stream>>>(X, hl, batch, ev);
        pool_kernel<<<NG, 256, 0, stream>>>(X, ev, hl, gst, qstar);
    }
    final_kernel<<<(NG * 64 + 255) / 256, 256, 0, stream>>>(qstar, lin3_w, lin3_b, out);
}

// Round 11
// 1854.765 us; speedup vs baseline: 13.2345x; 13.2345x over previous
//
#include <hip/hip_runtime.h>

#define DIM 64
#define NN 20000
#define NE 50000
#define NG 256
#define CONV_STEPS 12
#define S2S 3

typedef float floatx4 __attribute__((ext_vector_type(4)));
typedef short short8 __attribute__((ext_vector_type(8)));

__device__ __forceinline__ unsigned short f2bf(float f) {
    unsigned u = __float_as_uint(f);
    unsigned r = (u + 0x7fffu + ((u >> 16) & 1u)) >> 16;
    return (unsigned short)r;
}
__device__ __forceinline__ float bf2f(unsigned short h) {
    return __uint_as_float((unsigned)h << 16);
}
__device__ __forceinline__ float sigmoidf(float x) { return 1.f / (1.f + __expf(-x)); }
__device__ __forceinline__ float tanh_fast(float x) {
    float ax = fabsf(x);
    float t = __expf(-2.f * ax);
    float r = (1.f - t) / (1.f + t);
    return copysignf(r, x);
}
__device__ __forceinline__ float leaky(float v) { return v > 0.f ? v : 0.01f * v; }

// ---- prep: W2 -> bf16 fragment order; GRU/root weights -> bf16 hi/lo ----
__global__ __launch_bounds__(256) void prep_kernel(const float* __restrict__ w2,
        const float* __restrict__ wih, const float* __restrict__ whh,
        const float* __restrict__ rootw,
        unsigned short* __restrict__ w2f,
        unsigned short* __restrict__ wih_hi, unsigned short* __restrict__ wih_lo,
        unsigned short* __restrict__ whh_hi, unsigned short* __restrict__ whh_lo,
        unsigned short* __restrict__ rt_hi, unsigned short* __restrict__ rt_lo) {
    int idx = blockIdx.x * 256 + threadIdx.x;
    const int W2N = 4096 * 128, GT = 192 * 64;
    if (idx < W2N) {
        int j = idx >> 7, k = idx & 127;
        int jt = j >> 4, rw = j & 15;
        int kc = k >> 5, kq = (k >> 3) & 3, kb = k & 7;
        int dst = (((jt * 4 + kc) * 64) + kq * 16 + rw) * 8 + kb;
        w2f[dst] = f2bf(w2[idx]);
    } else if (idx < W2N + GT) {
        int t = idx - W2N;
        float v = wih[t];
        unsigned short h = f2bf(v);
        wih_hi[t] = h; wih_lo[t] = f2bf(v - bf2f(h));
    } else if (idx < W2N + 2 * GT) {
        int t = idx - W2N - GT;
        float v = whh[t];
        unsigned short h = f2bf(v);
        whh_hi[t] = h; whh_lo[t] = f2bf(v - bf2f(h));
    } else if (idx < W2N + 2 * GT + 4096) {
        int t = idx - W2N - 2 * GT;
        int o = t >> 6, k = t & 63;
        float v = rootw[k * 64 + o];          // rootT[o][k] = root_w[k][o]
        unsigned short h = f2bf(v);
        rt_hi[t] = h; rt_lo[t] = f2bf(v - bf2f(h));
    }
}

// ---- h1 = leaky(edge_attr @ net_w1.T + b1), bf16 [NE,128] ----
__global__ __launch_bounds__(256) void h1_kernel(const float* __restrict__ ea,
        const float* __restrict__ w1, const float* __restrict__ b1, unsigned short* __restrict__ h1) {
    int idx = blockIdx.x * 256 + threadIdx.x;
    if (idx >= NE * 128) return;
    int e = idx >> 7, k = idx & 127;
    const float* a = ea + (size_t)e * 4;
    const float* w = w1 + (size_t)k * 4;
    float acc = b1[k] + a[0] * w[0] + a[1] * w[1] + a[2] * w[2] + a[3] * w[3];
    h1[idx] = f2bf(leaky(acc));
}

// ---- lin0: X = leaky(x @ lin0_w.T + b), f32 [NN,64]; wave per node ----
__global__ __launch_bounds__(256) void lin0_kernel(const float* __restrict__ x,
        const float* __restrict__ w, const float* __restrict__ b, float* __restrict__ X) {
    int gid = blockIdx.x * 256 + threadIdx.x;
    int n = gid >> 6, o = gid & 63;
    if (n >= NN) return;
    float acc = b[o];
    const float* xr = x + (size_t)n * 72;
    const float* wr = w + (size_t)o * 72;
    #pragma unroll 8
    for (int i = 0; i < 72; ++i) acc += xr[i] * wr[i];
    X[(size_t)n * 64 + o] = leaky(acc);
}

// ---- XB2[n,o] = sum_i X[n,i] * b2[i*64+o] ----
__global__ __launch_bounds__(256) void xb2_kernel(const float* __restrict__ X,
        const float* __restrict__ b2, float* __restrict__ XB2) {
    int gid = blockIdx.x * 256 + threadIdx.x;
    int n = gid >> 6, lane = gid & 63;
    if (n >= NN) return;
    float xv = X[(size_t)n * 64 + lane];
    float acc = 0.f;
    #pragma unroll 8
    for (int i = 0; i < 64; ++i) acc += __shfl(xv, i) * b2[i * 64 + lane];
    XB2[(size_t)n * 64 + lane] = acc;
}

// ---- degree of dst nodes ----
__global__ __launch_bounds__(256) void deg_kernel(const int* __restrict__ ei, float* __restrict__ deg) {
    int e = blockIdx.x * 256 + threadIdx.x;
    if (e < NE) atomicAdd(&deg[ei[NE + e]], 1.f);
}

// ---- per-graph node range starts (batch is sorted) ----
__global__ void gstart_kernel(const int* __restrict__ batch, int* __restrict__ gstart) {
    int g = blockIdx.x * blockDim.x + threadIdx.x;
    if (g > NG) return;
    int lo = 0, hi = NN;
    while (lo < hi) { int mid = (lo + hi) >> 1; if (batch[mid] < g) lo = mid + 1; else hi = mid; }
    gstart[g] = lo;
}

// ---- fused edge messages (v4 EXACT — measured 107 us, VGPR 80, no spill):
// barrier-free K-loop; coalesced fragment-order B-loads; NO explicit prefetch
// (v5's register prefetch caused scratch spill: FETCH 27MB -> 3.4GB. Do not
// hold more than ~4 B-frags + A-frags live; compiler remats A from L1.)
__global__ __launch_bounds__(256, 3) void edge_msg_fused(
        const unsigned short* __restrict__ h1,   // [NE,128] bf16
        const unsigned short* __restrict__ w2f,  // fragment order
        const float* __restrict__ XB2,           // [NN,64] f32 bias term
        const float* __restrict__ X,             // [NN,64] f32
        const int* __restrict__ ei, float* __restrict__ agg) {
    __shared__ float xs_t[32][64];               // [ib_local][edge_local] 8 KB
    int tid = threadIdx.x;
    int e0b = blockIdx.x * 64;
    int ibBase = blockIdx.y * 32;
    bool useBias = (blockIdx.y == 0);

    {   // stage X transposed
        int e_l = tid & 63, q = tid >> 6;
        int e = e0b + e_l; if (e >= NE) e = NE - 1;
        int src = ei[e];
        const float4* xr = (const float4*)(X + (size_t)src * 64 + ibBase + q * 8);
        float4 v0 = xr[0], v1 = xr[1];
        int f0 = q * 8;
        xs_t[f0 + 0][e_l] = v0.x; xs_t[f0 + 1][e_l] = v0.y;
        xs_t[f0 + 2][e_l] = v0.z; xs_t[f0 + 3][e_l] = v0.w;
        xs_t[f0 + 4][e_l] = v1.x; xs_t[f0 + 5][e_l] = v1.y;
        xs_t[f0 + 6][e_l] = v1.z; xs_t[f0 + 7][e_l] = v1.w;
    }

    int wv = tid >> 6, lane = tid & 63;
    int oh = wv;
    int row = lane & 15, kq = lane >> 4;

    // A-frags hoisted (compiler remats from L1 as needed)
    short8 afr[4][4];
    #pragma unroll
    for (int mt = 0; mt < 4; ++mt) {
        int e = e0b + mt * 16 + row; if (e >= NE) e = NE - 1;
        const short8* ap = (const short8*)(h1 + (size_t)e * 128 + kq * 8);
        #pragma unroll
        for (int kc = 0; kc < 4; ++kc) afr[mt][kc] = ap[kc * 4];
    }

    floatx4 msg[4];
    #pragma unroll
    for (int mt = 0; mt < 4; ++mt) {
        #pragma unroll
        for (int r = 0; r < 4; ++r) {
            int e = e0b + mt * 16 + kq * 4 + r; if (e >= NE) e = NE - 1;
            msg[mt][r] = useBias ? XB2[(size_t)ei[e] * 64 + oh * 16 + row] : 0.f;
        }
    }

    __syncthreads();   // xs_t ready (only barrier)

    const short8* bbase = (const short8*)w2f;
    for (int il = 0; il < 32; ++il) {
        int tile = (ibBase + il) * 4 + oh;
        const short8* bp = bbase + (size_t)tile * 256 + lane;
        short8 bf[4];
        #pragma unroll
        for (int kc = 0; kc < 4; ++kc) bf[kc] = bp[kc * 64];   // coalesced 1KB each
        float4 xv[4];
        #pragma unroll
        for (int mt = 0; mt < 4; ++mt)
            xv[mt] = *(const float4*)&xs_t[il][mt * 16 + kq * 4];
        #pragma unroll
        for (int mt = 0; mt < 4; ++mt) {
            floatx4 acc = {0.f, 0.f, 0.f, 0.f};
            acc = __builtin_amdgcn_mfma_f32_16x16x32_bf16(afr[mt][0], bf[0], acc, 0, 0, 0);
            acc = __builtin_amdgcn_mfma_f32_16x16x32_bf16(afr[mt][1], bf[1], acc, 0, 0, 0);
            acc = __builtin_amdgcn_mfma_f32_16x16x32_bf16(afr[mt][2], bf[2], acc, 0, 0, 0);
            acc = __builtin_amdgcn_mfma_f32_16x16x32_bf16(afr[mt][3], bf[3], acc, 0, 0, 0);
            msg[mt][0] += xv[mt].x * acc[0];
            msg[mt][1] += xv[mt].y * acc[1];
            msg[mt][2] += xv[mt].z * acc[2];
            msg[mt][3] += xv[mt].w * acc[3];
        }
    }

    #pragma unroll
    for (int mt = 0; mt < 4; ++mt) {
        #pragma unroll
        for (int r = 0; r < 4; ++r) {
            int e = e0b + mt * 16 + kq * 4 + r;
            if (e < NE) {
                int dst = ei[NE + e];
                atomicAdd(&agg[(size_t)dst * 64 + oh * 16 + row], msg[mt][r]);
            }
        }
    }
}

// ---- node update v3: MFMA hi/lo, 4 fused accumulators (r,z fuse ih+hh into
// one C-matrix each). Acc VGPR 64 (was 96 in v2) — avoids scratch spill.
// block 256 = 4 waves, 64 nodes; wave wv owns feature slice ocol = wv*16+row.
__global__ __launch_bounds__(256) void node_update(float* __restrict__ X, float* __restrict__ agg,
        const float* __restrict__ deg,
        const unsigned short* __restrict__ rt_hi, const unsigned short* __restrict__ rt_lo,
        const unsigned short* __restrict__ wih_hi, const unsigned short* __restrict__ wih_lo,
        const unsigned short* __restrict__ whh_hi, const unsigned short* __restrict__ whh_lo,
        const float* __restrict__ conv_b,
        const float* __restrict__ bih, const float* __restrict__ bhh) {
    __shared__ unsigned short Xhi[64 * 72], Xlo[64 * 72];   // stride 72 (9x16B — ok for b128)
    __shared__ unsigned short Mhi[64 * 72], Mlo[64 * 72];
    int tid = threadIdx.x;
    int n0 = blockIdx.x * 64;

    // stage X as bf16 hi/lo
    for (int t = tid; t < 1024; t += 256) {
        int node = t >> 4, c = (t & 15) * 4;
        int n = n0 + node; if (n >= NN) n = NN - 1;
        float4 v = *(const float4*)(X + (size_t)n * 64 + c);
        float vv[4] = {v.x, v.y, v.z, v.w};
        #pragma unroll
        for (int j = 0; j < 4; ++j) {
            float xv = vv[j];
            unsigned short h = f2bf(xv);
            Xhi[node * 72 + c + j] = h;
            Xlo[node * 72 + c + j] = f2bf(xv - bf2f(h));
        }
    }
    __syncthreads();

    int wv = tid >> 6, lane = tid & 63;
    int row = lane & 15, kq = lane >> 4;
    int ocol = wv * 16 + row;

    // GEMM1: C1 = X @ rootT  (c1[node, ocol])
    floatx4 c1[4];
    #pragma unroll
    for (int mt = 0; mt < 4; ++mt) c1[mt] = (floatx4){0.f, 0.f, 0.f, 0.f};
    #pragma unroll
    for (int kc = 0; kc < 2; ++kc) {
        short8 bh = *(const short8*)(rt_hi + ocol * 64 + kc * 32 + kq * 8);
        short8 bl = *(const short8*)(rt_lo + ocol * 64 + kc * 32 + kq * 8);
        #pragma unroll
        for (int mt = 0; mt < 4; ++mt) {
            short8 ah = *(const short8*)&Xhi[(mt * 16 + row) * 72 + kc * 32 + kq * 8];
            short8 al = *(const short8*)&Xlo[(mt * 16 + row) * 72 + kc * 32 + kq * 8];
            c1[mt] = __builtin_amdgcn_mfma_f32_16x16x32_bf16(ah, bh, c1[mt], 0, 0, 0);
            c1[mt] = __builtin_amdgcn_mfma_f32_16x16x32_bf16(al, bh, c1[mt], 0, 0, 0);
            c1[mt] = __builtin_amdgcn_mfma_f32_16x16x32_bf16(ah, bl, c1[mt], 0, 0, 0);
        }
    }

    // m = leaky(agg/deg + C1 + cb) -> LDS hi/lo
    float cb = conv_b[ocol];
    #pragma unroll
    for (int mt = 0; mt < 4; ++mt) {
        #pragma unroll
        for (int r = 0; r < 4; ++r) {
            int node = mt * 16 + kq * 4 + r;
            int gn = n0 + node;
            float aggv = 0.f, dv = 1.f;
            if (gn < NN) {
                size_t id = (size_t)gn * 64 + ocol;
                aggv = agg[id]; agg[id] = 0.f;      // re-zero for next step
                dv = fmaxf(deg[gn], 1.f);
            }
            float m = leaky(aggv / dv + c1[mt][r] + cb);
            unsigned short h = f2bf(m);
            Mhi[node * 72 + ocol] = h;
            Mlo[node * 72 + ocol] = f2bf(m - bf2f(h));
        }
    }
    __syncthreads();

    // Gate GEMMs: 4 accumulators. ar = M@Wih_r + X@Whh_r (fused); az likewise;
    // ai = M@Wih_n; ah = X@Whh_n (kept separate for r*(...) in GRU).
    floatx4 ar[4], az[4], ai[4], ah_[4];
    #pragma unroll
    for (int mt = 0; mt < 4; ++mt) {
        ar[mt] = (floatx4){0.f,0.f,0.f,0.f}; az[mt] = ar[mt]; ai[mt] = ar[mt]; ah_[mt] = ar[mt];
    }
    #pragma unroll
    for (int kc = 0; kc < 2; ++kc) {
        int boff = ocol * 64 + kc * 32 + kq * 8;
        short8 birh = *(const short8*)(wih_hi + boff);
        short8 birl = *(const short8*)(wih_lo + boff);
        short8 bizh = *(const short8*)(wih_hi + 64 * 64 + boff);
        short8 bizl = *(const short8*)(wih_lo + 64 * 64 + boff);
        short8 binh = *(const short8*)(wih_hi + 128 * 64 + boff);
        short8 binl = *(const short8*)(wih_lo + 128 * 64 + boff);
        short8 bhrh = *(const short8*)(whh_hi + boff);
        short8 bhrl = *(const short8*)(whh_lo + boff);
        short8 bhzh = *(const short8*)(whh_hi + 64 * 64 + boff);
        short8 bhzl = *(const short8*)(whh_lo + 64 * 64 + boff);
        short8 bhnh = *(const short8*)(whh_hi + 128 * 64 + boff);
        short8 bhnl = *(const short8*)(whh_lo + 128 * 64 + boff);
        #pragma unroll
        for (int mt = 0; mt < 4; ++mt) {
            int aoff = (mt * 16 + row) * 72 + kc * 32 + kq * 8;
            short8 mh = *(const short8*)&Mhi[aoff];
            short8 ml = *(const short8*)&Mlo[aoff];
            short8 xh = *(const short8*)&Xhi[aoff];
            short8 xl = *(const short8*)&Xlo[aoff];
            ar[mt] = __builtin_amdgcn_mfma_f32_16x16x32_bf16(mh, birh, ar[mt], 0, 0, 0);
            ar[mt] = __builtin_amdgcn_mfma_f32_16x16x32_bf16(ml, birh, ar[mt], 0, 0, 0);
            ar[mt] = __builtin_amdgcn_mfma_f32_16x16x32_bf16(mh, birl, ar[mt], 0, 0, 0);
            ar[mt] = __builtin_amdgcn_mfma_f32_16x16x32_bf16(xh, bhrh, ar[mt], 0, 0, 0);
            ar[mt] = __builtin_amdgcn_mfma_f32_16x16x32_bf16(xl, bhrh, ar[mt], 0, 0, 0);
            ar[mt] = __builtin_amdgcn_mfma_f32_16x16x32_bf16(xh, bhrl, ar[mt], 0, 0, 0);
            az[mt] = __builtin_amdgcn_mfma_f32_16x16x32_bf16(mh, bizh, az[mt], 0, 0, 0);
            az[mt] = __builtin_amdgcn_mfma_f32_16x16x32_bf16(ml, bizh, az[mt], 0, 0, 0);
            az[mt] = __builtin_amdgcn_mfma_f32_16x16x32_bf16(mh, bizl, az[mt], 0, 0, 0);
            az[mt] = __builtin_amdgcn_mfma_f32_16x16x32_bf16(xh, bhzh, az[mt], 0, 0, 0);
            az[mt] = __builtin_amdgcn_mfma_f32_16x16x32_bf16(xl, bhzh, az[mt], 0, 0, 0);
            az[mt] = __builtin_amdgcn_mfma_f32_16x16x32_bf16(xh, bhzl, az[mt], 0, 0, 0);
            ai[mt] = __builtin_amdgcn_mfma_f32_16x16x32_bf16(mh, binh, ai[mt], 0, 0, 0);
            ai[mt] = __builtin_amdgcn_mfma_f32_16x16x32_bf16(ml, binh, ai[mt], 0, 0, 0);
            ai[mt] = __builtin_amdgcn_mfma_f32_16x16x32_bf16(mh, binl, ai[mt], 0, 0, 0);
            ah_[mt] = __builtin_amdgcn_mfma_f32_16x16x32_bf16(xh, bhnh, ah_[mt], 0, 0, 0);
            ah_[mt] = __builtin_amdgcn_mfma_f32_16x16x32_bf16(xl, bhnh, ah_[mt], 0, 0, 0);
            ah_[mt] = __builtin_amdgcn_mfma_f32_16x16x32_bf16(xh, bhnl, ah_[mt], 0, 0, 0);
        }
    }

    // GRU elementwise (lane: node = mt*16+kq*4+r, feat = ocol)
    float bi0 = bih[ocol], bi1 = bih[64 + ocol], bi2 = bih[128 + ocol];
    float bh0 = bhh[ocol], bh1 = bhh[64 + ocol], bh2 = bhh[128 + ocol];
    #pragma unroll
    for (int mt = 0; mt < 4; ++mt) {
        #pragma unroll
        for (int r = 0; r < 4; ++r) {
            int node = mt * 16 + kq * 4 + r;
            int gn = n0 + node;
            if (gn < NN) {
                float rr = sigmoidf(ar[mt][r] + bi0 + bh0);
                float zz = sigmoidf(az[mt][r] + bi1 + bh1);
                float nn = tanh_fast(ai[mt][r] + bi2 + rr * (ah_[mt][r] + bh2));
                float xs = X[(size_t)gn * 64 + ocol];
                X[(size_t)gn * 64 + ocol] = (1.f - zz) * nn + zz * xs;
            }
        }
    }
}

// ---- set2set LSTM step; block per graph ----
__global__ __launch_bounds__(256) void lstm_kernel(const float* __restrict__ qstar,
        float* __restrict__ hl, float* __restrict__ cl,
        const float* __restrict__ wih, const float* __restrict__ whh,
        const float* __restrict__ bih, const float* __restrict__ bhh) {
    int g = blockIdx.x, tid = threadIdx.x;
    __shared__ float qs[128], hs[64], gates[256];
    if (tid < 128) qs[tid] = qstar[(size_t)g * 128 + tid];
    else if (tid < 192) hs[tid - 128] = hl[(size_t)g * 64 + tid - 128];
    __syncthreads();
    float acc = bih[tid] + bhh[tid];
    const float* wr = wih + (size_t)tid * 128;
    #pragma unroll 8
    for (int k = 0; k < 128; ++k) acc += qs[k] * wr[k];
    const float* wr2 = whh + (size_t)tid * 64;
    #pragma unroll 8
    for (int k = 0; k < 64; ++k) acc += hs[k] * wr2[k];
    gates[tid] = acc;
    __syncthreads();
    if (tid < 64) {
        float gi = gates[tid], gf = gates[64 + tid], gg = gates[128 + tid], go = gates[192 + tid];
        float c = sigmoidf(gf) * cl[(size_t)g * 64 + tid] + sigmoidf(gi) * tanh_fast(gg);
        float h = sigmoidf(go) * tanh_fast(c);
        cl[(size_t)g * 64 + tid] = c;
        hl[(size_t)g * 64 + tid] = h;
    }
}

// ---- e[n] = dot(X[n], hl[batch[n]]); wave per node ----
__global__ __launch_bounds__(256) void e_kernel(const float* __restrict__ X, const float* __restrict__ hl,
        const int* __restrict__ batch, float* __restrict__ ev) {
    int gid = blockIdx.x * 256 + threadIdx.x;
    int n = gid >> 6, lane = gid & 63;
    if (n >= NN) return;
    int g = batch[n];
    float v = X[(size_t)n * 64 + lane] * hl[(size_t)g * 64 + lane];
    #pragma unroll
    for (int m = 32; m >= 1; m >>= 1) v += __shfl_xor(v, m);
    if (lane == 0) ev[n] = v;
}

// ---- per-graph softmax-attention readout ----
__global__ __launch_bounds__(256) void pool_kernel(const float* __restrict__ X, const float* __restrict__ ev,
        const float* __restrict__ hl, const int* __restrict__ gstart, float* __restrict__ qstar) {
    int g = blockIdx.x, tid = threadIdx.x;
    int s0 = gstart[g], s1 = gstart[g + 1];
    __shared__ float red[256];
    __shared__ float sh_max, sh_sum;
    float lm = -3.0e38f;
    for (int n = s0 + tid; n < s1; n += 256) lm = fmaxf(lm, ev[n]);
    red[tid] = lm; __syncthreads();
    for (int s = 128; s > 0; s >>= 1) { if (tid < s) red[tid] = fmaxf(red[tid], red[tid + s]); __syncthreads(); }
    if (tid == 0) sh_max = red[0];
    __syncthreads();
    float mx = sh_max;
    float ls = 0.f;
    for (int n = s0 + tid; n < s1; n += 256) ls += __expf(ev[n] - mx);
    __syncthreads();
    red[tid] = ls; __syncthreads();
    for (int s = 128; s > 0; s >>= 1) { if (tid < s) red[tid] += red[tid + s]; __syncthreads(); }
    if (tid == 0) sh_sum = red[0];
    __syncthreads();
    float inv = 1.f / (sh_sum + 1e-16f);
    int wv = tid >> 6, lane = tid & 63;
    float fa = 0.f;
    for (int n = s0 + wv; n < s1; n += 4) fa += __expf(ev[n] - mx) * inv * X[(size_t)n * 64 + lane];
    __syncthreads();
    red[tid] = fa; __syncthreads();
    if (tid < 64) {
        float r = red[tid] + red[64 + tid] + red[128 + tid] + red[192 + tid];
        qstar[(size_t)g * 128 + 64 + tid] = r;
        qstar[(size_t)g * 128 + tid] = hl[(size_t)g * 64 + tid];
    }
}

// ---- final: out[g] = q_star[g] . lin3_w + b ----
__global__ __launch_bounds__(256) void final_kernel(const float* __restrict__ qstar,
        const float* __restrict__ w3, const float* __restrict__ b3, float* __restrict__ out) {
    int gid = blockIdx.x * 256 + threadIdx.x;
    int g = gid >> 6, lane = gid & 63;
    if (g >= NG) return;
    float v = qstar[(size_t)g * 128 + lane] * w3[lane] + qstar[(size_t)g * 128 + 64 + lane] * w3[64 + lane];
    #pragma unroll
    for (int m = 32; m >= 1; m >>= 1) v += __shfl_xor(v, m);
    if (lane == 0) out[g] = v + b3[0];
}

extern "C" void kernel_launch(void* const* d_in, const int* in_sizes, int n_in,
                              void* d_out, int out_size, void* d_ws, size_t ws_size,
                              hipStream_t stream) {
    const float* x        = (const float*)d_in[0];
    const float* ea       = (const float*)d_in[1];
    const int*   ei       = (const int*)d_in[2];
    const int*   batch    = (const int*)d_in[3];
    const float* lin0_w   = (const float*)d_in[4];
    const float* lin0_b   = (const float*)d_in[5];
    const float* net_w1   = (const float*)d_in[6];
    const float* net_b1   = (const float*)d_in[7];
    const float* net_w2   = (const float*)d_in[8];
    const float* net_b2   = (const float*)d_in[9];
    const float* root_w   = (const float*)d_in[10];
    const float* conv_b   = (const float*)d_in[11];
    const float* gru_w_ih = (const float*)d_in[12];
    const float* gru_w_hh = (const float*)d_in[13];
    const float* gru_b_ih = (const float*)d_in[14];
    const float* gru_b_hh = (const float*)d_in[15];
    const float* lstm_w_ih= (const float*)d_in[16];
    const float* lstm_w_hh= (const float*)d_in[17];
    const float* lstm_b_ih= (const float*)d_in[18];
    const float* lstm_b_hh= (const float*)d_in[19];
    const float* lin3_w   = (const float*)d_in[20];
    const float* lin3_b   = (const float*)d_in[21];
    float* out = (float*)d_out;

    char* base = (char*)d_ws;
    size_t off = 0;
    auto alloc = [&](size_t b) { size_t o = off; off += (b + 255) & ~(size_t)255; return o; };
    size_t o_h1    = alloc((size_t)NE * 128 * 2);
    size_t o_X     = alloc((size_t)NN * 64 * 4);
    size_t o_agg   = alloc((size_t)NN * 64 * 4);
    size_t o_xb2   = alloc((size_t)NN * 64 * 4);
    size_t o_deg   = alloc((size_t)NN * 4);
    size_t o_ev    = alloc((size_t)NN * 4);
    size_t o_s2s   = alloc((size_t)(NG * 128 + NG * 64 + NG * 64) * 4);
    size_t o_gst   = alloc((size_t)(NG + 1) * 4);
    size_t o_w2f   = alloc((size_t)4096 * 128 * 2);
    size_t o_wihh  = alloc((size_t)192 * 64 * 2);
    size_t o_wihl  = alloc((size_t)192 * 64 * 2);
    size_t o_whhh  = alloc((size_t)192 * 64 * 2);
    size_t o_whhl  = alloc((size_t)192 * 64 * 2);
    size_t o_rth   = alloc((size_t)64 * 64 * 2);
    size_t o_rtl   = alloc((size_t)64 * 64 * 2);
    if (ws_size < off) return;  // needs ~32 MB

    unsigned short* h1   = (unsigned short*)(base + o_h1);
    float* X    = (float*)(base + o_X);
    float* agg  = (float*)(base + o_agg);
    float* XB2  = (float*)(base + o_xb2);
    float* deg  = (float*)(base + o_deg);
    float* ev   = (float*)(base + o_ev);
    float* qstar= (float*)(base + o_s2s);
    float* hl   = qstar + NG * 128;
    float* cl   = hl + NG * 64;
    int*   gst  = (int*)(base + o_gst);
    unsigned short* w2f    = (unsigned short*)(base + o_w2f);
    unsigned short* wih_hi = (unsigned short*)(base + o_wihh);
    unsigned short* wih_lo = (unsigned short*)(base + o_wihl);
    unsigned short* whh_hi = (unsigned short*)(base + o_whhh);
    unsigned short* whh_lo = (unsigned short*)(base + o_whhl);
    unsigned short* rt_hi  = (unsigned short*)(base + o_rth);
    unsigned short* rt_lo  = (unsigned short*)(base + o_rtl);

    hipMemsetAsync(deg, 0, (size_t)NN * 4, stream);
    hipMemsetAsync(agg, 0, (size_t)NN * 64 * 4, stream);
    hipMemsetAsync(qstar, 0, (size_t)(NG * 128 + NG * 64 + NG * 64) * 4, stream);

    const int PREP_N = 4096 * 128 + 2 * 192 * 64 + 64 * 64;
    prep_kernel<<<(PREP_N + 255) / 256, 256, 0, stream>>>(
        net_w2, gru_w_ih, gru_w_hh, root_w, w2f,
        wih_hi, wih_lo, whh_hi, whh_lo, rt_hi, rt_lo);
    h1_kernel<<<(NE * 128 + 255) / 256, 256, 0, stream>>>(ea, net_w1, net_b1, h1);
    lin0_kernel<<<(NN * 64 + 255) / 256, 256, 0, stream>>>(x, lin0_w, lin0_b, X);
    deg_kernel<<<(NE + 255) / 256, 256, 0, stream>>>(ei, deg);
    gstart_kernel<<<2, 256, 0, stream>>>(batch, gst);

    const dim3 EGRID((NE + 63) / 64, 2);
    const int NBLK = (NN + 63) / 64;
    for (int s = 0; s < CONV_STEPS; ++s) {
        xb2_kernel<<<(NN * 64 + 255) / 256, 256, 0, stream>>>(X, net_b2, XB2);
        edge_msg_fused<<<EGRID, 256, 0, stream>>>(h1, w2f, XB2, X, ei, agg);
        node_update<<<NBLK, 256, 0, stream>>>(
            X, agg, deg, rt_hi, rt_lo, wih_hi, wih_lo, whh_hi, whh_lo,
            conv_b, gru_b_ih, gru_b_hh);
    }

    for (int s = 0; s < S2S; ++s) {
        lstm_kernel<<<NG, 256, 0, stream>>>(qstar, hl, cl, lstm_w_ih, lstm_w_hh, lstm_b_ih, lstm_b_hh);
        e_kernel<<<(NN * 64 + 255) / 256, 256, 0, stream>>>(X, hl, batch, ev);
        pool_kernel<<<NG, 256, 0, stream>>>(X, ev, hl, gst, qstar);
    }
    final_kernel<<<(NG * 64 + 255) / 256, 256, 0, stream>>>(qstar, lin3_w, lin3_b, out);
}